// Round 16
// baseline (299.089 us; speedup 1.0000x reference)
//
#include <hip/hip_runtime.h>
#include <hip/hip_bf16.h>

// Problem constants (fixed by setup_inputs)
#define B_    2
#define H_    32
#define KVH_  8
#define T_    4096
#define C_    4096
#define D_    128
#define W_    512
#define KTOP  1024
#define TOUT  (T_ + KTOP)      // 5120
#define QB    64               // queries per block
#define NQB   (W_/QB)          // 8
#define TB2   128              // keys per tile (4 waves x 32k)
#define NTT2  (T_/TB2)         // 32 tiles
#define NPART (H_*NQB)         // 256 partial slices per batch
#define NBLK  (NQB*H_*B_)      // 512 blocks (flat grid)
// SCALE * log2(e): scores computed directly in 2^x domain (exp2 == v_exp_f32)
#define SLOG2E 0.12751744f

typedef __attribute__((ext_vector_type(8))) _Float16 half8;
typedef __attribute__((ext_vector_type(4))) float f32x4;
typedef __attribute__((ext_vector_type(16))) float f32x16;

__device__ __forceinline__ void gload16(const void* g, void* l) {
    __builtin_amdgcn_global_load_lds(
        (const __attribute__((address_space(1))) void*)g,
        (__attribute__((address_space(3))) void*)l, 16, 0, 0);
}

// ---------------------------------------------------------------------------
// Kernel 0: convert km (f32) -> split f16 hi/lo, pre-swizzled tile layout.
// Per (b,kvh): [tile64][r=0..63][128 cols], col d stored at d ^ ((r&7)<<3).
// (Same layout as before: a 32-row aligned span stays inside one 64-row tile,
//  so TB2=128 staging reads two contiguous 32-row spans per wave pair.)
// ---------------------------------------------------------------------------
__global__ __launch_bounds__(256) void convert_k_kernel(
    const float* __restrict__ km, _Float16* __restrict__ Khw,
    _Float16* __restrict__ Klw)
{
    int g = blockIdx.x*256 + threadIdx.x;     // granule id (8 elements)
    size_t e = (size_t)g*8;
    int d0 = (int)(e & 127);
    size_t row = e >> 7;                      // bk*T + t
    int t = (int)(row & (T_-1));
    size_t bk = row >> 12;
    int r = t & 63, tt = t >> 6;
    size_t off = (bk<<19) + (size_t)tt*(64*D_) + (size_t)r*D_ + (d0 ^ ((r&7)<<3));
    float4 v0 = *(const float4*)(km + e);
    float4 v1 = *(const float4*)(km + e + 4);
    float f[8] = {v0.x,v0.y,v0.z,v0.w,v1.x,v1.y,v1.z,v1.w};
    half8 hh, hl;
#pragma unroll
    for (int i = 0; i < 8; ++i) {
        _Float16 hi = (_Float16)f[i];
        hh[i] = hi;
        hl[i] = (_Float16)(f[i] - (float)hi);
    }
    *(half8*)&Khw[off] = hh;
    *(half8*)&Klw[off] = hl;
}

// ---- per-wave staging: wave kg owns keys kg*32..kg*32+31 of each tile -----
// 8 issues x 1KB per dtype per tile (32 rows x 256B).
#define STAGE_T(gbase, t, buf)                                              \
    {                                                                       \
        const _Float16* g_ = (gbase) + (size_t)(t)*16384;                   \
        _Pragma("unroll")                                                   \
        for (int i_ = 0; i_ < 8; ++i_)                                      \
            gload16(g_ + i_*512, (buf) + i_*512 + lane*8);                  \
    }

// ds_read this lane's 8 B-fragments (chunk c: d = c*16 + hi*8, swizzled)
#define READF(buf, kf)                                                      \
    _Pragma("unroll")                                                       \
    for (int c_ = 0; c_ < 8; ++c_)                                          \
        kf[c_] = *(const half8*)&(buf)[rr*128 + ((c_*16 + hi*8) ^ xsw)];

// 16 MFMA of 32x32x16 (2 M-tiles x 8 K-chunks) for one Q operand set
#define MFMA_T(qf, kf, acc)                                                 \
    {                                                                       \
        __builtin_amdgcn_s_setprio(1);                                      \
        _Pragma("unroll")                                                   \
        for (int c_ = 0; c_ < 8; ++c_) {                                    \
            acc[0] = __builtin_amdgcn_mfma_f32_32x32x16_f16(qf[0][c_], kf[c_], acc[0], 0,0,0); \
            acc[1] = __builtin_amdgcn_mfma_f32_32x32x16_f16(qf[1][c_], kf[c_], acc[1], 0,0,0); \
        }                                                                   \
        __builtin_amdgcn_s_setprio(0);                                      \
    }

// ---------------------------------------------------------------------------
// Fused importance kernel, 32x32x16 MFMA shape (wall: 66 -> 55 us).
// Block = (qb, h, b): 64 queries x 4096 keys, 4 waves, wave tile 64q x 32k
// (2 M-tiles x 8 K-chunks), TB2=128, NTT2=32. LDS 16KB/wave (64KB/block,
// 2 blocks/CU). Pass 1: Kh ping-pong across the two 8KB halves, counted
// vmcnt(8), single-term qh*kh (l rel-err ~1e-5 << 1e-4 budget). Pass 2:
// single-buffered Kh+Kl, read-to-regs -> lgkm(0)+sched_barrier -> restage-
// in-place (split H/L so restage latency hides under term MFMAs), 3-term
// qh*kh + ql*kh + qh*kl (score err ~1e-7). Scores in 2^x domain (Q pre-
// scaled by SCALE*log2e). Fragment maps: A/B row|col = lane&31,
// k = (lane>>5)*8+e; C/D col=lane&31, row=(reg&3)+8*(reg>>2)+4*(lane>>5)
// (guide m74/m101). All reductions fixed-order -> deterministic.
// VGPR budget: Q 128 + kf 32 (Kh/Kl time-shared) + rv 32 + acc 32 (AGPR)
// + misc ~ 245 <= 256 cap at (256,2).
// ---------------------------------------------------------------------------
__global__ __launch_bounds__(256, 2) void fused_imp_kernel(
    const float* __restrict__ q_w, const _Float16* __restrict__ Khw,
    const _Float16* __restrict__ Klw, float* __restrict__ partial)
{
    __shared__ __align__(16) _Float16 sK[4][8192];   // 16KB per wave
    __shared__ float sL[4][QB];
    __shared__ float sR[QB];

    const int tid = threadIdx.x, wid = tid >> 6, lane = tid & 63;
    const int rr = lane & 31, hi = lane >> 5;
    const int xsw = (rr & 7) << 3;
    const int kg = wid;                       // wave = key group (32 rows)

    // flat decode with XCD grouping: 32 blocks sharing one (b,kvh) K-slice
    // sit on one XCD (2 slices x 2MB per XCD L2).
    const int flat = blockIdx.x;
    const int xcd = flat & 7, m = flat >> 3;
    const int g = (m >> 5)*8 + xcd;           // 0..15 = (b,kvh)
    const int r = m & 31;                     // (hh, qb)
    const int kvh = g & 7, b = g >> 3;
    const int hh = r >> 3, qb = r & 7;
    const int h = kvh*4 + hh;

    // Q fragments (A operand): row = m*32 + (lane&31), k-chunk c: d =
    // c*16 + hi*8 + e. Pre-scaled by SCALE*log2e, hi/lo f16 split. 128 VGPR.
    half8 qh[2][8], ql[2][8];
    {
        const float* qp0 = q_w + (((size_t)b*H_ + h)*W_ + qb*QB + rr)*D_;
#pragma unroll
        for (int mm = 0; mm < 2; ++mm)
#pragma unroll
            for (int c = 0; c < 8; ++c) {
                const float* p = qp0 + mm*32*D_ + c*16 + hi*8;
                float4 v0 = *(const float4*)p;
                float4 v1 = *(const float4*)(p+4);
                float f[8] = {v0.x,v0.y,v0.z,v0.w,v1.x,v1.y,v1.z,v1.w};
#pragma unroll
                for (int e = 0; e < 8; ++e) {
                    float fs = f[e] * SLOG2E;
                    _Float16 hv = (_Float16)fs;
                    qh[mm][c][e] = hv;
                    ql[mm][c][e] = (_Float16)(fs - (float)hv);
                }
            }
    }

    const size_t kvoff = ((size_t)b*KVH_ + kvh) * ((size_t)T_*D_);
    // wave's 32 keys of tile t start at global key t*128 + kg*32:
    // half-index = (t*2 + (kg>>1))*8192 + (kg&1)*4096  (64-row global tiles)
    const _Float16* gh0 = Khw + kvoff + (size_t)(kg>>1)*8192
                        + (size_t)(kg&1)*4096 + (size_t)lane*8;
    const _Float16* gl0 = Klw + kvoff + (size_t)(kg>>1)*8192
                        + (size_t)(kg&1)*4096 + (size_t)lane*8;
    _Float16* ldsA = &sK[wid][0];
    _Float16* ldsB = &sK[wid][4096];

    half8 kf[8];
    f32x16 acc[2];
    float lacc[2][16] = {};

    // ---- pass 1: softmax denominators (Kh only, single-term, ping-pong) ----
    STAGE_T(gh0, 0, ldsA);
    STAGE_T(gh0, 1, ldsB);
    for (int t = 0; t < NTT2; ++t) {
        if (t + 1 < NTT2) { asm volatile("s_waitcnt vmcnt(8)" ::: "memory"); }
        else              { asm volatile("s_waitcnt vmcnt(0)" ::: "memory"); }
        _Float16* cur = (t & 1) ? ldsB : ldsA;
        READF(cur, kf);
        asm volatile("s_waitcnt lgkmcnt(0)" ::: "memory");
        __builtin_amdgcn_sched_barrier(0);
        if (t + 2 < NTT2) STAGE_T(gh0, t+2, cur);
        acc[0] = (f32x16)(0.f); acc[1] = (f32x16)(0.f);
        MFMA_T(qh, kf, acc);
#pragma unroll
        for (int mm = 0; mm < 2; ++mm)
#pragma unroll
            for (int rg = 0; rg < 16; ++rg)
                lacc[mm][rg] += __builtin_amdgcn_exp2f(acc[mm][rg]);
    }

    // reduce over this wave's 32 keys (lanes sharing hi), then over kg
#pragma unroll
    for (int mm = 0; mm < 2; ++mm)
#pragma unroll
        for (int rg = 0; rg < 16; ++rg) {
            float v = lacc[mm][rg];
            v += __shfl_xor(v, 1);  v += __shfl_xor(v, 2);
            v += __shfl_xor(v, 4);  v += __shfl_xor(v, 8);
            v += __shfl_xor(v, 16);
            if (rr == 0)
                sL[kg][mm*32 + (rg&3) + 8*(rg>>2) + 4*hi] = v;
        }
    __syncthreads();
    if (tid < QB) {
        float l = sL[0][tid] + sL[1][tid] + sL[2][tid] + sL[3][tid];
        sR[tid] = 1.0f / l;
    }
    __syncthreads();
    float rv[2][16];
#pragma unroll
    for (int mm = 0; mm < 2; ++mm)
#pragma unroll
        for (int rg = 0; rg < 16; ++rg)
            rv[mm][rg] = sR[mm*32 + (rg&3) + 8*(rg>>2) + 4*hi];

    // ---- pass 2: per-key weight sums (3-term), single-buffer restage ----
    const size_t po = (((size_t)(h*NQB + qb))*B_ + b)*T_;
    STAGE_T(gh0, 0, ldsA);
    STAGE_T(gl0, 0, ldsB);
    for (int t = 0; t < NTT2; ++t) {
        asm volatile("s_waitcnt vmcnt(0)" ::: "memory");
        // Kh fragments -> regs, then restage Kh(t+1) in place
        READF(ldsA, kf);
        asm volatile("s_waitcnt lgkmcnt(0)" ::: "memory");
        __builtin_amdgcn_sched_barrier(0);
        if (t + 1 < NTT2) STAGE_T(gh0, t+1, ldsA);
        acc[0] = (f32x16)(0.f); acc[1] = (f32x16)(0.f);
        MFMA_T(qh, kf, acc);       // term 1: qh*kh
        MFMA_T(ql, kf, acc);       // term 2: ql*kh
        // Kl fragments -> same regs, then restage Kl(t+1)
        READF(ldsB, kf);
        asm volatile("s_waitcnt lgkmcnt(0)" ::: "memory");
        __builtin_amdgcn_sched_barrier(0);
        if (t + 1 < NTT2) STAGE_T(gl0, t+1, ldsB);
        MFMA_T(qh, kf, acc);       // term 3: qh*kl
        float x = 0.f;
#pragma unroll
        for (int mm = 0; mm < 2; ++mm)
#pragma unroll
            for (int rg = 0; rg < 16; ++rg)
                x += __builtin_amdgcn_exp2f(acc[mm][rg]) * rv[mm][rg];
        x += __shfl_xor(x, 32);    // combine the two hi-halves (all 64 q)
        if (lane < 32)
            partial[po + (size_t)t*TB2 + kg*32 + lane] = x;
    }
}

// ---------------------------------------------------------------------------
// Kernel 2: deterministic fixed-order reduce over 256 partial slices, /H.
// ---------------------------------------------------------------------------
__global__ __launch_bounds__(256) void imp_reduce_kernel(
    const float* __restrict__ partial, float* __restrict__ imp)
{
    int gid = blockIdx.x*256 + threadIdx.x;   // 8192 = B*T
    int b = gid >> 12, t = gid & (T_-1);
    float s = 0.f;
    for (int i = 0; i < NPART; ++i)
        s += partial[((size_t)(i*B_ + b))*T_ + t];
    imp[gid] = s * (1.0f/H_);
}

// ---------------------------------------------------------------------------
// Kernel 3: per-batch radix top-k select (desc, idx-asc ties) + prefix scan.
// ---------------------------------------------------------------------------
__global__ __launch_bounds__(1024) void topk_kernel(
    const float* __restrict__ imp, int* __restrict__ mask, int* __restrict__ start)
{
    __shared__ int hist[256];
    __shared__ int sa[1024], sb[1024];
    __shared__ int sbin, srem;
    const int tid = threadIdx.x, b = blockIdx.x;
    const int i0 = 4*tid;

    unsigned key[4];
#pragma unroll
    for (int j = 0; j < 4; ++j) {
        unsigned u = __float_as_uint(imp[b*T_ + i0 + j]);
        key[j] = (u & 0x80000000u) ? ~u : (u | 0x80000000u);
    }

    unsigned prefix = 0;
    int k_rem = KTOP;
#pragma unroll
    for (int sh = 24; sh >= 0; sh -= 8) {
        unsigned hi_mask = (sh == 24) ? 0u : (0xFFFFFFFFu << (sh + 8));
        if (tid < 256) hist[tid] = 0;
        __syncthreads();
#pragma unroll
        for (int j = 0; j < 4; ++j)
            if ((key[j] & hi_mask) == prefix)
                atomicAdd(&hist[(key[j] >> sh) & 255], 1);
        __syncthreads();
        if (tid == 0) {
            int acc = 0, bin = 255;
            for (; bin > 0; --bin) {
                int hv = hist[bin];
                if (acc + hv >= k_rem) break;
                acc += hv;
            }
            sbin = bin; srem = k_rem - acc;
        }
        __syncthreads();
        prefix |= ((unsigned)sbin) << sh;
        k_rem = srem;
        __syncthreads();
    }

    int m[4], eq[4];
#pragma unroll
    for (int j = 0; j < 4; ++j) {
        m[j]  = key[j] > prefix ? 1 : 0;
        eq[j] = (key[j] == prefix) ? 1 : 0;
    }
    // rank ties by index (stable top_k: lowest index wins)
    int e4 = eq[0]+eq[1]+eq[2]+eq[3];
    sa[tid] = e4;
    __syncthreads();
    {
        int *src = sa, *dst = sb;
        for (int off = 1; off < 1024; off <<= 1) {
            int v = src[tid];
            if (tid >= off) v += src[tid - off];
            dst[tid] = v;
            __syncthreads();
            int* t2 = src; src = dst; dst = t2;
        }
        int r = src[tid] - e4;
#pragma unroll
        for (int j = 0; j < 4; ++j) {
            if (eq[j] && r < k_rem) m[j] = 1;
            r += eq[j];
        }
    }
    __syncthreads();
    // sizes scan -> output row positions
    int s4 = m[0]+m[1]+m[2]+m[3];
    sa[tid] = s4;
    __syncthreads();
    int *src = sa, *dst = sb;
    for (int off = 1; off < 1024; off <<= 1) {
        int v = src[tid];
        if (tid >= off) v += src[tid - off];
        dst[tid] = v;
        __syncthreads();
        int* t2 = src; src = dst; dst = t2;
    }
    int excl = src[tid] - s4;
    start[b*T_+i0+0] = i0+0 + excl;
    start[b*T_+i0+1] = i0+1 + excl + m[0];
    start[b*T_+i0+2] = i0+2 + excl + m[0]+m[1];
    start[b*T_+i0+3] = i0+3 + excl + m[0]+m[1]+m[2];
    mask[b*T_+i0+0] = m[0]; mask[b*T_+i0+1] = m[1];
    mask[b*T_+i0+2] = m[2]; mask[b*T_+i0+3] = m[3];
}

// ---------------------------------------------------------------------------
// Kernel 4: scatter-copy rows (nontemporal streaming copy; f32x4 ext_vector
// type — HIP float4 is a struct and rejected by __builtin_nontemporal_*).
// ---------------------------------------------------------------------------
__global__ __launch_bounds__(256) void scatter_kernel(
    const float* __restrict__ x_m, const float* __restrict__ xm_cmp,
    const int* __restrict__ mask, const int* __restrict__ start,
    float* __restrict__ out)
{
    const int t = blockIdx.x, b = blockIdx.y, tid = threadIdx.x;
    const int mk = mask[b*T_+t];
    const int st = start[b*T_+t];
    const float* s1 = mk ? (x_m + ((size_t)b*2*T_ + 2*t)*C_)
                         : (xm_cmp + ((size_t)b*T_ + t)*C_);
    f32x4* d1 = (f32x4*)(out + ((size_t)b*TOUT + st)*C_);
    const f32x4* s1v = (const f32x4*)s1;
    for (int i = tid; i < C_/4; i += 256) {
        f32x4 v = __builtin_nontemporal_load(s1v + i);
        __builtin_nontemporal_store(v, d1 + i);
    }
    if (mk) {
        const f32x4* s2v = (const f32x4*)(x_m + ((size_t)b*2*T_ + 2*t+1)*C_);
        f32x4* d2 = d1 + C_/4;
        for (int i = tid; i < C_/4; i += 256) {
            f32x4 v = __builtin_nontemporal_load(s2v + i);
            __builtin_nontemporal_store(v, d2 + i);
        }
    }
}

extern "C" void kernel_launch(void* const* d_in, const int* in_sizes, int n_in,
                              void* d_out, int out_size, void* d_ws, size_t ws_size,
                              hipStream_t stream)
{
    (void)in_sizes; (void)n_in; (void)out_size; (void)ws_size;
    const float* x_m    = (const float*)d_in[0];
    const float* xm_cmp = (const float*)d_in[1];
    const float* q_w    = (const float*)d_in[2];
    const float* km     = (const float*)d_in[3];
    float* out = (float*)d_out;

    char* ws = (char*)d_ws;
    _Float16* Khw   = (_Float16*)ws;                              // 16 MB
    _Float16* Klw   = (_Float16*)(ws + 16777216);                 // 16 MB
    float* partial  = (float*)(ws + 33554432);                    // 8 MB
    float* imp      = (float*)(ws + 41943040);                    // 32 KB
    int*   mask     = (int*)  (ws + 41975808);                    // 32 KB
    int*   start    = (int*)  (ws + 42008576);                    // 32 KB

    convert_k_kernel<<<dim3(4096), dim3(256), 0, stream>>>(km, Khw, Klw);
    fused_imp_kernel<<<dim3(NBLK), dim3(256), 0, stream>>>(q_w, Khw, Klw, partial);
    imp_reduce_kernel<<<dim3((B_*T_)/256), dim3(256), 0, stream>>>(partial, imp);
    topk_kernel<<<dim3(B_), dim3(1024), 0, stream>>>(imp, mask, start);
    scatter_kernel<<<dim3(T_, B_), dim3(256), 0, stream>>>(x_m, xm_cmp, mask, start, out);
}

// Round 17
// 263.470 us; speedup vs baseline: 1.1352x; 1.1352x over previous
//
#include <hip/hip_runtime.h>
#include <hip/hip_bf16.h>

// Problem constants (fixed by setup_inputs)
#define B_    2
#define H_    32
#define KVH_  8
#define T_    4096
#define C_    4096
#define D_    128
#define W_    512
#define KTOP  1024
#define TOUT  (T_ + KTOP)      // 5120
#define QB    64               // queries per block (one 64q wave-tile)
#define NQB   (W_/QB)          // 8
#define TB    64               // keys per tile
#define NTT   (T_/TB)          // 64 tiles (full key range per block)
#define NPART (H_*NQB)         // 256 partial slices per batch
#define NBLK  (NQB*H_*B_)      // 512 blocks (flat grid)
// SCALE * log2(e): scores computed directly in 2^x domain (exp2 == v_exp_f32)
#define SLOG2E 0.12751744f

typedef __attribute__((ext_vector_type(8))) _Float16 half8;
typedef __attribute__((ext_vector_type(4))) float f32x4;

__device__ __forceinline__ void gload16(const void* g, void* l) {
    __builtin_amdgcn_global_load_lds(
        (const __attribute__((address_space(1))) void*)g,
        (__attribute__((address_space(3))) void*)l, 16, 0, 0);
}

// ---------------------------------------------------------------------------
// Kernel 0: convert km (f32) -> split f16 hi/lo, pre-swizzled tile layout.
// Per (b,kvh): [tile][r=0..63][128 cols], col d stored at d ^ ((r&7)<<3).
// ---------------------------------------------------------------------------
__global__ __launch_bounds__(256) void convert_k_kernel(
    const float* __restrict__ km, _Float16* __restrict__ Khw,
    _Float16* __restrict__ Klw)
{
    int g = blockIdx.x*256 + threadIdx.x;     // granule id (8 elements)
    size_t e = (size_t)g*8;
    int d0 = (int)(e & 127);
    size_t row = e >> 7;                      // bk*T + t
    int t = (int)(row & (T_-1));
    size_t bk = row >> 12;
    int r = t & 63, tt = t >> 6;
    size_t off = (bk<<19) + (size_t)tt*(TB*D_) + (size_t)r*D_ + (d0 ^ ((r&7)<<3));
    float4 v0 = *(const float4*)(km + e);
    float4 v1 = *(const float4*)(km + e + 4);
    float f[8] = {v0.x,v0.y,v0.z,v0.w,v1.x,v1.y,v1.z,v1.w};
    half8 hh, hl;
#pragma unroll
    for (int i = 0; i < 8; ++i) {
        _Float16 hi = (_Float16)f[i];
        hh[i] = hi;
        hl[i] = (_Float16)(f[i] - (float)hi);
    }
    *(half8*)&Khw[off] = hh;
    *(half8*)&Klw[off] = hl;
}

// ---- per-wave staging: wave wid owns K rows wid*16..wid*16+15 -------------
// Pass 1 stages Kh only (4 x 1KB issues); pass 2 stages Kh+Kl (8 issues).
#define STAGE1(bufidx, tt)                                                  \
    {                                                                       \
        const _Float16* gh_ = gh0 + (size_t)(tt)*8192;                      \
        gload16(gh_,        &sKh[bufidx][wid][lane*8]);                     \
        gload16(gh_ + 512,  &sKh[bufidx][wid][512 + lane*8]);               \
        gload16(gh_ + 1024, &sKh[bufidx][wid][1024 + lane*8]);              \
        gload16(gh_ + 1536, &sKh[bufidx][wid][1536 + lane*8]);              \
    }

#define STAGE2(bufidx, tt)                                                  \
    {                                                                       \
        const _Float16* gh_ = gh0 + (size_t)(tt)*8192;                      \
        const _Float16* gl_ = gl0 + (size_t)(tt)*8192;                      \
        gload16(gh_,        &sKh[bufidx][wid][lane*8]);                     \
        gload16(gh_ + 512,  &sKh[bufidx][wid][512 + lane*8]);               \
        gload16(gh_ + 1024, &sKh[bufidx][wid][1024 + lane*8]);              \
        gload16(gh_ + 1536, &sKh[bufidx][wid][1536 + lane*8]);              \
        gload16(gl_,        &sKl[bufidx][wid][lane*8]);                     \
        gload16(gl_ + 512,  &sKl[bufidx][wid][512 + lane*8]);               \
        gload16(gl_ + 1024, &sKl[bufidx][wid][1024 + lane*8]);              \
        gload16(gl_ + 1536, &sKl[bufidx][wid][1536 + lane*8]);              \
    }

// Pass-1 MFMA: SINGLE-term qh*kh. l sums 4096 exp terms; the dropped
// ql*kh error (~3.4e-4, zero-mean across keys) averages to l rel-err
// ~1e-5 << 1e-4 budget. Halves pass-1 MFMA vs 2-term.
#define MFMA1(bufidx, acc)                                                  \
    {                                                                       \
        const _Float16* bKh = sKh[bufidx][wid];                             \
        __builtin_amdgcn_s_setprio(1);                                      \
        _Pragma("unroll")                                                   \
        for (int ks2 = 0; ks2 < 4; ++ks2) {                                 \
            const int off = li*D_ + ((ks2*32 + lg*8) ^ ((li & 7) << 3));    \
            half8 bh = *(const half8*)&bKh[off];                            \
            _Pragma("unroll")                                               \
            for (int mm = 0; mm < 4; ++mm)                                  \
                acc[mm] = __builtin_amdgcn_mfma_f32_16x16x32_f16(qh[mm][ks2], bh, acc[mm], 0,0,0); \
        }                                                                   \
        __builtin_amdgcn_s_setprio(0);                                      \
    }

// Pass-2 MFMA: 3-term split qh*kh + ql*kh + qh*kl (score err ~1e-7).
#define MFMA3(bufidx, acc)                                                  \
    {                                                                       \
        const _Float16* bKh = sKh[bufidx][wid];                             \
        const _Float16* bKl = sKl[bufidx][wid];                             \
        __builtin_amdgcn_s_setprio(1);                                      \
        _Pragma("unroll")                                                   \
        for (int ks2 = 0; ks2 < 4; ++ks2) {                                 \
            const int off = li*D_ + ((ks2*32 + lg*8) ^ ((li & 7) << 3));    \
            half8 bh = *(const half8*)&bKh[off];                            \
            half8 bl = *(const half8*)&bKl[off];                            \
            _Pragma("unroll")                                               \
            for (int mm = 0; mm < 4; ++mm)                                  \
                acc[mm] = __builtin_amdgcn_mfma_f32_16x16x32_f16(qh[mm][ks2], bh, acc[mm], 0,0,0); \
            _Pragma("unroll")                                               \
            for (int mm = 0; mm < 4; ++mm)                                  \
                acc[mm] = __builtin_amdgcn_mfma_f32_16x16x32_f16(ql[mm][ks2], bh, acc[mm], 0,0,0); \
            _Pragma("unroll")                                               \
            for (int mm = 0; mm < 4; ++mm)                                  \
                acc[mm] = __builtin_amdgcn_mfma_f32_16x16x32_f16(qh[mm][ks2], bl, acc[mm], 0,0,0); \
        }                                                                   \
        __builtin_amdgcn_s_setprio(0);                                      \
    }

// Softmax-denominator accumulate for a finished tile (overlaps next MFMA).
#define EXPACC(acc)                                                         \
    _Pragma("unroll")                                                       \
    for (int mm = 0; mm < 4; ++mm)                                          \
        _Pragma("unroll")                                                   \
        for (int j = 0; j < 4; ++j)                                         \
            lacc[mm][j] += __builtin_amdgcn_exp2f(acc[mm][j]);

// Weight-sum + store for a finished tile t (overlaps next MFMA).
#define EXPSTORE(acc, t)                                                    \
    {                                                                       \
        float x = 0.f;                                                      \
        _Pragma("unroll")                                                   \
        for (int mm = 0; mm < 4; ++mm)                                      \
            _Pragma("unroll")                                               \
            for (int j = 0; j < 4; ++j)                                     \
                x += __builtin_amdgcn_exp2f(acc[mm][j]) * rv[mm][j];        \
        x += __shfl_xor(x, 16); x += __shfl_xor(x, 32);                     \
        if (lg == 0)                                                        \
            partial[po + (size_t)(t)*TB + kg*16 + li] = x;                  \
    }

#define P1BODY(t, ACCD, ACCE)                                               \
    {                                                                       \
        STAGE1(((t)+1) & 1, (t)+1);                                         \
        asm volatile("s_waitcnt vmcnt(4)" ::: "memory");                    \
        MFMA1((t) & 1, ACCD);                                               \
        EXPACC(ACCE);                                                       \
    }

#define P2BODY(t, ACCD, ACCE)                                               \
    {                                                                       \
        STAGE2(((t)+1) & 1, (t)+1);                                         \
        asm volatile("s_waitcnt vmcnt(9)" ::: "memory");                    \
        MFMA3((t) & 1, ACCD);                                               \
        EXPSTORE(ACCE, (t)-1);                                              \
    }

#define ACCZERO(acc)                                                        \
    _Pragma("unroll")                                                       \
    for (int mm = 0; mm < 4; ++mm) acc[mm] = (f32x4){0.f,0.f,0.f,0.f};

// ---------------------------------------------------------------------------
// Fused importance kernel (R11/R15 best-measured config, restored verbatim).
// Block = (qb, h, b): 64 queries x 4096 keys, 4 waves, wave tile 64q x 16k,
// barrier-free tile loop (counted vmcnt only), acc ping-pong so exp(t-1)
// overlaps MFMA(t). Scores in 2^x domain (Q pre-scaled by SCALE*log2e).
// Pass 1: l[q] via SINGLE-term (Kh only). Pass 2: 3-term split, direct
// stores. All reductions fixed-order -> deterministic.
// ---------------------------------------------------------------------------
__global__ __launch_bounds__(256, 2) void fused_imp_kernel(
    const float* __restrict__ q_w, const _Float16* __restrict__ Khw,
    const _Float16* __restrict__ Klw, float* __restrict__ partial)
{
    __shared__ __align__(16) _Float16 sKh[2][4][16*D_];
    __shared__ __align__(16) _Float16 sKl[2][4][16*D_];
    __shared__ float sL[4][QB];
    __shared__ float sR[QB];

    const int tid = threadIdx.x, wid = tid >> 6, lane = tid & 63;
    const int lg = lane >> 4, li = lane & 15;
    const int kg = wid;                       // wave = key group

    // flat decode with XCD grouping: 32 blocks sharing one (b,kvh) K-slice
    // sit on one XCD (2 slices x 2MB per XCD L2).
    const int flat = blockIdx.x;
    const int xcd = flat & 7, m = flat >> 3;
    const int g = (m >> 5)*8 + xcd;           // 0..15 = (b,kvh)
    const int r = m & 31;                     // (hh, qb)
    const int kvh = g & 7, b = g >> 3;
    const int hh = r >> 3, qb = r & 7;
    const int h = kvh*4 + hh;

    // Q fragments: all 64 q of the block per wave (mm=4), pre-scaled by
    // SCALE*log2e, then hi/lo f16 split.
    half8 qh[4][4], ql[4][4];
    {
        const float* qp0 = q_w + (((size_t)b*H_ + h)*W_ + qb*QB + li)*D_;
#pragma unroll
        for (int mm = 0; mm < 4; ++mm)
#pragma unroll
            for (int ks2 = 0; ks2 < 4; ++ks2) {
                const float* p = qp0 + mm*16*D_ + ks2*32 + lg*8;
                float4 v0 = *(const float4*)p;
                float4 v1 = *(const float4*)(p+4);
                float f[8] = {v0.x,v0.y,v0.z,v0.w,v1.x,v1.y,v1.z,v1.w};
#pragma unroll
                for (int e = 0; e < 8; ++e) {
                    float fs = f[e] * SLOG2E;
                    _Float16 hv = (_Float16)fs;
                    qh[mm][ks2][e] = hv;
                    ql[mm][ks2][e] = (_Float16)(fs - (float)hv);
                }
            }
    }

    const size_t kvoff = ((size_t)b*KVH_ + kvh) * ((size_t)T_*D_);
    // wave's own 16 rows start at wid*2048 halfs within each 8192-half tile
    const _Float16* gh0 = Khw + kvoff + (size_t)wid*2048 + (size_t)lane*8;
    const _Float16* gl0 = Klw + kvoff + (size_t)wid*2048 + (size_t)lane*8;

    float lacc[4][4] = {};
    f32x4 accA[4], accB[4];

    // ---- pass 1: softmax denominators (Kh only, single-term) ----
    STAGE1(0, 0);
    STAGE1(1, 1);
    asm volatile("s_waitcnt vmcnt(4)" ::: "memory");
    ACCZERO(accA);
    MFMA1(0, accA);
    for (int t = 1; t < NTT-1; t += 2) {
        ACCZERO(accB);
        P1BODY(t,   accB, accA);
        ACCZERO(accA);
        P1BODY(t+1, accA, accB);
    }
    // final tile 63 (loads already issued by body t=62)
    asm volatile("s_waitcnt vmcnt(0)" ::: "memory");
    ACCZERO(accB);
    MFMA1(1, accB);
    EXPACC(accA);
    EXPACC(accB);

    // reduce over li (16 keys of this wave's kg column), then over kg
#pragma unroll
    for (int mm = 0; mm < 4; ++mm)
#pragma unroll
        for (int j = 0; j < 4; ++j) {
            float v = lacc[mm][j];
            v += __shfl_xor(v, 1); v += __shfl_xor(v, 2);
            v += __shfl_xor(v, 4); v += __shfl_xor(v, 8);
            if (li == 0) sL[kg][mm*16 + lg*4 + j] = v;
        }
    __syncthreads();
    if (tid < QB) {
        float l = sL[0][tid] + sL[1][tid] + sL[2][tid] + sL[3][tid];
        sR[tid] = 1.0f / l;
    }
    __syncthreads();
    float rv[4][4];
#pragma unroll
    for (int mm = 0; mm < 4; ++mm)
#pragma unroll
        for (int j = 0; j < 4; ++j)
            rv[mm][j] = sR[mm*16 + lg*4 + j];

    // ---- pass 2: per-key weight sums (3-term split), direct stores ----
    const size_t po = (((size_t)(h*NQB + qb))*B_ + b)*T_;
    STAGE2(0, 0);
    STAGE2(1, 1);
    asm volatile("s_waitcnt vmcnt(8)" ::: "memory");
    ACCZERO(accA);
    MFMA3(0, accA);
    for (int t = 1; t < NTT-1; t += 2) {
        ACCZERO(accB);
        P2BODY(t,   accB, accA);
        ACCZERO(accA);
        P2BODY(t+1, accA, accB);
    }
    // final tile 63
    asm volatile("s_waitcnt vmcnt(1)" ::: "memory");
    ACCZERO(accB);
    MFMA3(1, accB);
    EXPSTORE(accA, NTT-2);
    EXPSTORE(accB, NTT-1);
}

// ---------------------------------------------------------------------------
// Kernel 2: deterministic fixed-order reduce over 256 partial slices, /H.
// ---------------------------------------------------------------------------
__global__ __launch_bounds__(256) void imp_reduce_kernel(
    const float* __restrict__ partial, float* __restrict__ imp)
{
    int gid = blockIdx.x*256 + threadIdx.x;   // 8192 = B*T
    int b = gid >> 12, t = gid & (T_-1);
    float s = 0.f;
    for (int i = 0; i < NPART; ++i)
        s += partial[((size_t)(i*B_ + b))*T_ + t];
    imp[gid] = s * (1.0f/H_);
}

// ---------------------------------------------------------------------------
// Kernel 3: per-batch radix top-k select (desc, idx-asc ties) + prefix scan.
// ---------------------------------------------------------------------------
__global__ __launch_bounds__(1024) void topk_kernel(
    const float* __restrict__ imp, int* __restrict__ mask, int* __restrict__ start)
{
    __shared__ int hist[256];
    __shared__ int sa[1024], sb[1024];
    __shared__ int sbin, srem;
    const int tid = threadIdx.x, b = blockIdx.x;
    const int i0 = 4*tid;

    unsigned key[4];
#pragma unroll
    for (int j = 0; j < 4; ++j) {
        unsigned u = __float_as_uint(imp[b*T_ + i0 + j]);
        key[j] = (u & 0x80000000u) ? ~u : (u | 0x80000000u);
    }

    unsigned prefix = 0;
    int k_rem = KTOP;
#pragma unroll
    for (int sh = 24; sh >= 0; sh -= 8) {
        unsigned hi_mask = (sh == 24) ? 0u : (0xFFFFFFFFu << (sh + 8));
        if (tid < 256) hist[tid] = 0;
        __syncthreads();
#pragma unroll
        for (int j = 0; j < 4; ++j)
            if ((key[j] & hi_mask) == prefix)
                atomicAdd(&hist[(key[j] >> sh) & 255], 1);
        __syncthreads();
        if (tid == 0) {
            int acc = 0, bin = 255;
            for (; bin > 0; --bin) {
                int hv = hist[bin];
                if (acc + hv >= k_rem) break;
                acc += hv;
            }
            sbin = bin; srem = k_rem - acc;
        }
        __syncthreads();
        prefix |= ((unsigned)sbin) << sh;
        k_rem = srem;
        __syncthreads();
    }

    int m[4], eq[4];
#pragma unroll
    for (int j = 0; j < 4; ++j) {
        m[j]  = key[j] > prefix ? 1 : 0;
        eq[j] = (key[j] == prefix) ? 1 : 0;
    }
    // rank ties by index (stable top_k: lowest index wins)
    int e4 = eq[0]+eq[1]+eq[2]+eq[3];
    sa[tid] = e4;
    __syncthreads();
    {
        int *src = sa, *dst = sb;
        for (int off = 1; off < 1024; off <<= 1) {
            int v = src[tid];
            if (tid >= off) v += src[tid - off];
            dst[tid] = v;
            __syncthreads();
            int* t2 = src; src = dst; dst = t2;
        }
        int r = src[tid] - e4;
#pragma unroll
        for (int j = 0; j < 4; ++j) {
            if (eq[j] && r < k_rem) m[j] = 1;
            r += eq[j];
        }
    }
    __syncthreads();
    // sizes scan -> output row positions
    int s4 = m[0]+m[1]+m[2]+m[3];
    sa[tid] = s4;
    __syncthreads();
    int *src = sa, *dst = sb;
    for (int off = 1; off < 1024; off <<= 1) {
        int v = src[tid];
        if (tid >= off) v += src[tid - off];
        dst[tid] = v;
        __syncthreads();
        int* t2 = src; src = dst; dst = t2;
    }
    int excl = src[tid] - s4;
    start[b*T_+i0+0] = i0+0 + excl;
    start[b*T_+i0+1] = i0+1 + excl + m[0];
    start[b*T_+i0+2] = i0+2 + excl + m[0]+m[1];
    start[b*T_+i0+3] = i0+3 + excl + m[0]+m[1]+m[2];
    mask[b*T_+i0+0] = m[0]; mask[b*T_+i0+1] = m[1];
    mask[b*T_+i0+2] = m[2]; mask[b*T_+i0+3] = m[3];
}

// ---------------------------------------------------------------------------
// Kernel 4: scatter-copy rows (nontemporal streaming copy; f32x4 ext_vector
// type — HIP float4 is a struct and rejected by __builtin_nontemporal_*).
// ---------------------------------------------------------------------------
__global__ __launch_bounds__(256) void scatter_kernel(
    const float* __restrict__ x_m, const float* __restrict__ xm_cmp,
    const int* __restrict__ mask, const int* __restrict__ start,
    float* __restrict__ out)
{
    const int t = blockIdx.x, b = blockIdx.y, tid = threadIdx.x;
    const int mk = mask[b*T_+t];
    const int st = start[b*T_+t];
    const float* s1 = mk ? (x_m + ((size_t)b*2*T_ + 2*t)*C_)
                         : (xm_cmp + ((size_t)b*T_ + t)*C_);
    f32x4* d1 = (f32x4*)(out + ((size_t)b*TOUT + st)*C_);
    const f32x4* s1v = (const f32x4*)s1;
    for (int i = tid; i < C_/4; i += 256) {
        f32x4 v = __builtin_nontemporal_load(s1v + i);
        __builtin_nontemporal_store(v, d1 + i);
    }
    if (mk) {
        const f32x4* s2v = (const f32x4*)(x_m + ((size_t)b*2*T_ + 2*t+1)*C_);
        f32x4* d2 = d1 + C_/4;
        for (int i = tid; i < C_/4; i += 256) {
            f32x4 v = __builtin_nontemporal_load(s2v + i);
            __builtin_nontemporal_store(v, d2 + i);
        }
    }
}

extern "C" void kernel_launch(void* const* d_in, const int* in_sizes, int n_in,
                              void* d_out, int out_size, void* d_ws, size_t ws_size,
                              hipStream_t stream)
{
    (void)in_sizes; (void)n_in; (void)out_size; (void)ws_size;
    const float* x_m    = (const float*)d_in[0];
    const float* xm_cmp = (const float*)d_in[1];
    const float* q_w    = (const float*)d_in[2];
    const float* km     = (const float*)d_in[3];
    float* out = (float*)d_out;

    char* ws = (char*)d_ws;
    _Float16* Khw   = (_Float16*)ws;                              // 16 MB
    _Float16* Klw   = (_Float16*)(ws + 16777216);                 // 16 MB
    float* partial  = (float*)(ws + 33554432);                    // 8 MB
    float* imp      = (float*)(ws + 41943040);                    // 32 KB
    int*   mask     = (int*)  (ws + 41975808);                    // 32 KB
    int*   start    = (int*)  (ws + 42008576);                    // 32 KB

    convert_k_kernel<<<dim3(4096), dim3(256), 0, stream>>>(km, Khw, Klw);
    fused_imp_kernel<<<dim3(NBLK), dim3(256), 0, stream>>>(q_w, Khw, Klw, partial);
    imp_reduce_kernel<<<dim3((B_*T_)/256), dim3(256), 0, stream>>>(partial, imp);
    topk_kernel<<<dim3(B_), dim3(1024), 0, stream>>>(imp, mask, start);
    scatter_kernel<<<dim3(T_, B_), dim3(256), 0, stream>>>(x_m, xm_cmp, mask, start, out);
}